// Round 7
// baseline (1474.333 us; speedup 1.0000x reference)
//
#include <hip/hip_runtime.h>
#include <hip/hip_fp16.h>

typedef _Float16 half2v __attribute__((ext_vector_type(2)));

#define B_ 64
#define T_ 512
#define H_ 256
#define G4_ 1024
#define IN_ 60
#define O_ 402

#define NAGQ 45    // weight quads per thread in AGPRs (180 dwords)
#define NLDSQ 19   // weight quads per thread in LDS   (155648 B)

// Quad routing: quad jq = cc*4+q (cc = k-chunk 0..15, q = gate 0..3).
// LDS-resident: q==3 (all chunks) plus q==2 of chunks 13..15  -> 19 quads,
// interleaved across chunks so LDS reads overlap AGPR/VALU work.
__host__ __device__ __forceinline__ constexpr bool is_lds_q(int jq) {
  int cc = jq >> 2, q = jq & 3;
  return (q == 3) || (q == 2 && cc >= 13);
}
__host__ __device__ __forceinline__ constexpr int lds_slot(int jq) {
  int cc = jq >> 2, q = jq & 3;
  return (q == 3) ? cc : 16 + (cc - 13);
}
__host__ __device__ __forceinline__ constexpr int ag_slot(int jq) {
  int cc = jq >> 2;
  return jq - (cc + (cc >= 13 ? cc - 13 : 0));   // jq minus #lds before it
}

__device__ __forceinline__ float fdot2(unsigned int a, unsigned int b, float c) {
  return __builtin_amdgcn_fdot2(__builtin_bit_cast(half2v, a),
                                __builtin_bit_cast(half2v, b), c, false);
}

__device__ __forceinline__ unsigned int pack_h2(float a, float b) {
  unsigned short ua = __half_as_ushort(__float2half(a));
  unsigned short ub = __half_as_ushort(__float2half(b));
  return (unsigned int)ua | ((unsigned int)ub << 16);
}

__device__ __forceinline__ float sigmoid_f(float x) {
  return __fdividef(1.0f, 1.0f + __expf(-x));
}
__device__ __forceinline__ float tanh_f(float x) {
  float ax = fminf(fabsf(x) * 2.0f, 40.0f);
  float e = __expf(ax);
  float r = __fdividef(e - 1.0f, e + 1.0f);
  return copysignf(r, x);
}

// ---------------- K0: weight packing / permutation ----------------
// xg gate permutation: packed col r' = 4*u + q <-> original row q*256 + u.
// W_hh layout for k2 (512 threads): thread l = (u=l>>1, hf=l&1) owns all 4
// gate rows of unit u over k-half hf (128 k = 64 pair-dwords = 16 quads).
// Quad routing per is_lds_q/ag_slot/lds_slot. Stream layout [(slot)*512+l].
__global__ __launch_bounds__(256) void k0_pack(
    const float* __restrict__ wih, const float* __restrict__ whh,
    const float* __restrict__ bih, const float* __restrict__ bhh,
    const float* __restrict__ wfc,
    float* __restrict__ wpih, float* __restrict__ biasp,
    unsigned int* __restrict__ wreg_ws, unsigned int* __restrict__ wlds_ws,
    unsigned int* __restrict__ wfcp) {
  int idx = blockIdx.x * 256 + threadIdx.x;
  if (idx < 61440) {                       // Wp_ih[k][r'] = W_ih[orig(r')][k]
    int k = idx / 1024, rp = idx % 1024;
    int orig = (rp & 3) * 256 + (rp >> 2);
    wpih[idx] = wih[orig * IN_ + k];
  } else if (idx < 62464) {                // bias_p[r'] = b_ih[orig]+b_hh[orig]
    int rp = idx - 61440;
    int orig = (rp & 3) * 256 + (rp >> 2);
    biasp[rp] = bih[orig] + bhh[orig];
  } else if (idx < 193536) {               // W_hh -> f16 pairs, k2 layout
    int i2 = idx - 62464;                  // 0..131071
    int l = i2 >> 8;                       // k2 thread 0..511
    int i = i2 & 255;                      // dword within thread
    int jq = i >> 2, p = i & 3;
    int cc = jq >> 2, q = jq & 3;
    int u = l >> 1, hf = l & 1;
    int P = hf * 64 + cc * 4 + p;          // k-pair index: covers k=2P,2P+1
    int row = q * 256 + u;                 // original gate row
    unsigned int pk = pack_h2(whh[row * 256 + 2 * P], whh[row * 256 + 2 * P + 1]);
    if (!is_lds_q(jq)) wreg_ws[(ag_slot(jq) * 512 + l) * 4 + p] = pk;
    else               wlds_ws[(lds_slot(jq) * 512 + l) * 4 + p] = pk;
  } else if (idx < 244992) {               // W_fc -> f16 pairs
    int i3 = idx - 193536;
    int o = i3 >> 7, P = i3 & 127;
    wfcp[o * 128 + P] = pack_h2(wfc[o * 256 + 2 * P], wfc[o * 256 + 2 * P + 1]);
  }
}

// ---------------- K1: xg = x @ W_ih^T + b_ih + b_hh (permuted cols) ---------
template <bool F32>
__global__ __launch_bounds__(256, 2) void k1_xgemm(
    const float* __restrict__ x, const float* __restrict__ wpih,
    const float* __restrict__ biasp, void* __restrict__ xg_v) {
  __shared__ float xt[IN_ * 64];           // xt[k][bt]
  const int l = threadIdx.x, blk = blockIdx.x;
  for (int i = l; i < IN_ * 64; i += 256) {
    int k = i >> 6, bt = i & 63;
    xt[i] = x[(size_t)(blk * 64 + bt) * IN_ + k];
  }
  __syncthreads();
  float4 bias4 = *(const float4*)&biasp[4 * l];
  float* xg_f = (float*)xg_v;
  unsigned int* xg_h = (unsigned int*)xg_v;
  for (int half = 0; half < 2; ++half) {   // 2 chunks of 32 bt-rows
    float4 a[32];
#pragma unroll
    for (int j = 0; j < 32; ++j) a[j] = bias4;
    for (int k = 0; k < IN_; ++k) {
      float4 w4 = *(const float4*)&wpih[k * G4_ + 4 * l];
#pragma unroll
      for (int j4 = 0; j4 < 8; ++j4) {
        float4 xv = *(const float4*)&xt[k * 64 + half * 32 + j4 * 4];
        float xs[4] = {xv.x, xv.y, xv.z, xv.w};
#pragma unroll
        for (int jj = 0; jj < 4; ++jj) {
          float xc = xs[jj];
          float4& A = a[j4 * 4 + jj];
          A.x = fmaf(w4.x, xc, A.x); A.y = fmaf(w4.y, xc, A.y);
          A.z = fmaf(w4.z, xc, A.z); A.w = fmaf(w4.w, xc, A.w);
        }
      }
    }
#pragma unroll
    for (int j = 0; j < 32; ++j) {
      size_t bt = (size_t)blk * 64 + half * 32 + j;
      if constexpr (F32) {
        *(float4*)&xg_f[bt * G4_ + 4 * l] = a[j];
      } else {
        uint2 pk;
        pk.x = pack_h2(a[j].x, a[j].y);
        pk.y = pack_h2(a[j].z, a[j].w);
        *(uint2*)&xg_h[bt * (G4_ / 2) + 2 * l] = pk;
      }
    }
  }
}

// ---------------- K2: sequential LSTM, 1 block per batch row ----------------
// 512 threads = 8 waves = 2 waves/SIMD (256 unified regs/thread budget).
// Thread l = (u=l>>1, hf=l&1): all 4 gates of unit u over 128 k values.
// Weights: 180 dwords AGPR-pinned (asm, the r2/r3-proven residency mechanism)
// + 76 dwords in LDS, interleaved across chunks. Working set kept lean
// (per-quad temps, no staging array) so 180 + arch <= 256 holds.
template <bool F32>
__global__ __launch_bounds__(512, 2) void k2_lstm(
    const void* __restrict__ xg_v, const uint4* __restrict__ wreg_ws,
    const uint4* __restrict__ wlds_ws, unsigned short* __restrict__ hs) {
  __shared__ uint4 wlds[NLDSQ * 512];                   // 155648 B
  __shared__ unsigned int hq4[2][2][68];                // padded h dbuf, 1088 B
  const int l = threadIdx.x;
  const int b = blockIdx.x;
  const int hf = l & 1;
  for (int i = l; i < NLDSQ * 512; i += 512) wlds[i] = wlds_ws[i];
  if (l < 64)        hq4[0][0][l] = 0u;                 // h(0) = 0
  else if (l < 128)  hq4[0][1][l - 64] = 0u;

  unsigned int wa[NAGQ * 4];                            // 180 AGPR-pinned dwords
#pragma unroll
  for (int j = 0; j < NAGQ; ++j) {
    uint4 v = wreg_ws[j * 512 + l];
    asm("v_accvgpr_write_b32 %0, %1" : "=a"(wa[4 * j + 0]) : "v"(v.x));
    asm("v_accvgpr_write_b32 %0, %1" : "=a"(wa[4 * j + 1]) : "v"(v.y));
    asm("v_accvgpr_write_b32 %0, %1" : "=a"(wa[4 * j + 2]) : "v"(v.z));
    asm("v_accvgpr_write_b32 %0, %1" : "=a"(wa[4 * j + 3]) : "v"(v.w));
  }

  const unsigned int* xgu = (const unsigned int*)xg_v;  // f16: dword bt*512+l
  const float2* xgf2 = (const float2*)xg_v;             // f32: float2 bt*512+l
  float2 xf2; unsigned int xh;
  if constexpr (F32) xf2 = xgf2[(size_t)b * T_ * 512 + l];
  else               xh  = xgu[(size_t)b * T_ * 512 + l];
  float c = 0.0f;
  __syncthreads();
  for (int t = 0; t < T_; ++t) {
    float lo, hi;
    if constexpr (F32) { lo = xf2.x; hi = xf2.y; }
    else {
      half2v p = __builtin_bit_cast(half2v, xh);
      lo = (float)p[0]; hi = (float)p[1];
    }
    // hf=0 lane seeds gates i,f; hf=1 lane seeds gates g,o
    float a0 = hf ? 0.0f : lo, a1 = hf ? 0.0f : hi;
    float a2 = hf ? lo : 0.0f, a3 = hf ? hi : 0.0f;
    int tn = (t < T_ - 1) ? (t + 1) : t;                // prefetch next xg
    if constexpr (F32) xf2 = xgf2[(size_t)(b * T_ + tn) * 512 + l];
    else               xh  = xgu[(size_t)(b * T_ + tn) * 512 + l];

    const uint4* hB = (const uint4*)hq4[t & 1][hf];     // 16 quads of h-half
#pragma unroll
    for (int cc = 0; cc < 16; ++cc) {
      uint4 hq = hB[cc];
#pragma unroll
      for (int q = 0; q < 4; ++q) {
        const int jq = cc * 4 + q;
        unsigned int w0, w1, w2, w3;
        if (is_lds_q(jq)) {
          uint4 v = wlds[lds_slot(jq) * 512 + l];
          w0 = v.x; w1 = v.y; w2 = v.z; w3 = v.w;
        } else {
          const int as = ag_slot(jq);
          asm("v_accvgpr_read_b32 %0, %1" : "=v"(w0) : "a"(wa[4*as+0]), "v"(t));
          asm("v_accvgpr_read_b32 %0, %1" : "=v"(w1) : "a"(wa[4*as+1]), "v"(t));
          asm("v_accvgpr_read_b32 %0, %1" : "=v"(w2) : "a"(wa[4*as+2]), "v"(t));
          asm("v_accvgpr_read_b32 %0, %1" : "=v"(w3) : "a"(wa[4*as+3]), "v"(t));
        }
        float& aq = (q == 0) ? a0 : (q == 1) ? a1 : (q == 2) ? a2 : a3;
        aq = fdot2(w0, hq.x, aq); aq = fdot2(w1, hq.y, aq);
        aq = fdot2(w2, hq.z, aq); aq = fdot2(w3, hq.w, aq);
      }
    }
    // combine the two k-halves (partner lane adjacent in same wave)
    a0 += __shfl_xor(a0, 1); a1 += __shfl_xor(a1, 1);
    a2 += __shfl_xor(a2, 1); a3 += __shfl_xor(a3, 1);
    // gating (redundant on both lanes of the pair)
    float ig = sigmoid_f(a0), fg = sigmoid_f(a1);
    float gg = tanh_f(a2),    og = sigmoid_f(a3);
    c = fg * c + ig * gg;
    float h = og * tanh_f(c);
    unsigned int hbits = (unsigned int)__half_as_ushort(__float2half(h));
    unsigned int hnext = (unsigned int)__shfl_xor((int)hbits, 2); // unit u+1
    if ((l & 3) == 0) {                                 // one dword per 2 units
      unsigned int pk = hbits | (hnext << 16);
      int d = l >> 2;                                   // dword 0..127
      hq4[(t & 1) ^ 1][d >> 6][d & 63] = pk;
      ((unsigned int*)hs)[(size_t)(b * T_ + t) * 128 + d] = pk;
    }
    __syncthreads();                                    // h(t) visible to all
  }
}

// ---------------- K3: out = hs @ W_fc^T + b_fc ----------------
__global__ __launch_bounds__(256, 2) void k3_out(
    const unsigned short* __restrict__ hs, const unsigned int* __restrict__ wfcp,
    const float* __restrict__ bfc, float* __restrict__ out) {
  __shared__ unsigned int ht[64 * 128];            // 64 bt-rows of h (f16 pairs)
  const int l = threadIdx.x, blk = blockIdx.x;
  const unsigned int* hsrc = (const unsigned int*)hs + (size_t)blk * 64 * 128;
  for (int i = l; i < 64 * 128; i += 256) ht[i] = hsrc[i];
  __syncthreads();
  const int c1 = l;
  const int c2 = 256 + l;
  const bool has2 = (c2 < O_);
  const int c2r = has2 ? c2 : 0;
  float b1 = bfc[c1], b2 = bfc[c2r];
  for (int btc = 0; btc < 4; ++btc) {
    float a1[16], a2[16];
#pragma unroll
    for (int j = 0; j < 16; ++j) { a1[j] = b1; a2[j] = b2; }
    for (int Pc = 0; Pc < 8; ++Pc) {
      uint4 wq1[4], wq2[4];
#pragma unroll
      for (int p4 = 0; p4 < 4; ++p4) {
        wq1[p4] = *(const uint4*)&wfcp[c1 * 128 + Pc * 16 + 4 * p4];
        wq2[p4] = *(const uint4*)&wfcp[c2r * 128 + Pc * 16 + 4 * p4];
      }
#pragma unroll
      for (int j = 0; j < 16; ++j) {
        const unsigned int* hr = &ht[(btc * 16 + j) * 128 + Pc * 16];
#pragma unroll
        for (int p4 = 0; p4 < 4; ++p4) {
          uint4 hv = *(const uint4*)&hr[4 * p4];
          a1[j] = fdot2(wq1[p4].x, hv.x, a1[j]);
          a1[j] = fdot2(wq1[p4].y, hv.y, a1[j]);
          a1[j] = fdot2(wq1[p4].z, hv.z, a1[j]);
          a1[j] = fdot2(wq1[p4].w, hv.w, a1[j]);
          a2[j] = fdot2(wq2[p4].x, hv.x, a2[j]);
          a2[j] = fdot2(wq2[p4].y, hv.y, a2[j]);
          a2[j] = fdot2(wq2[p4].z, hv.z, a2[j]);
          a2[j] = fdot2(wq2[p4].w, hv.w, a2[j]);
        }
      }
    }
#pragma unroll
    for (int j = 0; j < 16; ++j) {
      size_t bt = (size_t)blk * 64 + btc * 16 + j;
      out[bt * O_ + c1] = a1[j];
      if (has2) out[bt * O_ + c2] = a2[j];
    }
  }
}

// ---------------- host ----------------
extern "C" void kernel_launch(void* const* d_in, const int* in_sizes, int n_in,
                              void* d_out, int out_size, void* d_ws, size_t ws_size,
                              hipStream_t stream) {
  const float* x   = (const float*)d_in[0];
  const float* wih = (const float*)d_in[1];
  const float* whh = (const float*)d_in[2];
  const float* bih = (const float*)d_in[3];
  const float* bhh = (const float*)d_in[4];
  const float* wfc = (const float*)d_in[5];
  const float* bfc = (const float*)d_in[6];
  float* out = (float*)d_out;
  char* ws = (char*)d_ws;

  const size_t HS_BYTES = (size_t)B_ * T_ * H_ * 2;
  const size_t XG_F32   = (size_t)B_ * T_ * G4_ * 4;
  const size_t WREG_B   = (size_t)NAGQ * 512 * 16;   // 368640
  const size_t WLDS_B   = (size_t)NLDSQ * 512 * 16;  // 155648
  const size_t WPIH_B   = (size_t)IN_ * G4_ * 4;
  const size_t BIAS_B   = (size_t)G4_ * 4;
  const size_t WFCP_B   = (size_t)O_ * 128 * 4;
  const size_t TAIL = HS_BYTES + WREG_B + WLDS_B + WPIH_B + BIAS_B + WFCP_B;

  bool f32xg = (ws_size >= XG_F32 + TAIL);
  size_t xg_bytes = f32xg ? XG_F32 : ((size_t)B_ * T_ * G4_ * 2);

  char* xg    = ws;
  char* hsb   = ws + xg_bytes;
  char* wregp = hsb + HS_BYTES;
  char* wldsp = wregp + WREG_B;
  char* wpihp = wldsp + WLDS_B;
  char* biasp = wpihp + WPIH_B;
  char* wfcpp = biasp + BIAS_B;

  hipLaunchKernelGGL(k0_pack, dim3(957), dim3(256), 0, stream,
                     wih, whh, bih, bhh, wfc,
                     (float*)wpihp, (float*)biasp,
                     (unsigned int*)wregp, (unsigned int*)wldsp,
                     (unsigned int*)wfcpp);
  if (f32xg) {
    hipLaunchKernelGGL((k1_xgemm<true>), dim3(512), dim3(256), 0, stream,
                       x, (const float*)wpihp, (const float*)biasp, (void*)xg);
    hipLaunchKernelGGL((k2_lstm<true>), dim3(64), dim3(512), 0, stream,
                       (const void*)xg, (const uint4*)wregp, (const uint4*)wldsp,
                       (unsigned short*)hsb);
  } else {
    hipLaunchKernelGGL((k1_xgemm<false>), dim3(512), dim3(256), 0, stream,
                       x, (const float*)wpihp, (const float*)biasp, (void*)xg);
    hipLaunchKernelGGL((k2_lstm<false>), dim3(64), dim3(512), 0, stream,
                       (const void*)xg, (const uint4*)wregp, (const uint4*)wldsp,
                       (unsigned short*)hsb);
  }
  hipLaunchKernelGGL(k3_out, dim3(512), dim3(256), 0, stream,
                     (const unsigned short*)hsb, (const unsigned int*)wfcpp,
                     bfc, out);
}

// Round 8
// 963.829 us; speedup vs baseline: 1.5297x; 1.5297x over previous
//
#include <hip/hip_runtime.h>
#include <hip/hip_fp16.h>

typedef _Float16 half2v __attribute__((ext_vector_type(2)));

#define B_ 64
#define T_ 512
#define H_ 256
#define G4_ 1024
#define IN_ 60
#define O_ 402

#define NREGQ 28   // weight quads per thread in plain VGPRs (112 dwords)
#define NLDSQ 19   // weight quads per thread in LDS (155648 B)
#define NSTRQ 17   // weight quads per thread streamed from L2 each step

// Quad routing: quad jq = cc*4+q (cc = k-chunk 0..15, q = gate 0..3).
//  VGPR:   q==0 (all cc)        + q==1 (cc>=4)   -> 28 quads
//  LDS:    q==3 (all cc)        + q==2 (cc>=13)  -> 19 quads
//  STREAM: q==1 (cc<4)          + q==2 (cc<13)   -> 17 quads
// Interleaved across chunks so VGPR/LDS/L2 pipes overlap every chunk.
__host__ __device__ __forceinline__ constexpr bool is_vgpr_q(int jq) {
  int cc = jq >> 2, q = jq & 3;
  return (q == 0) || (q == 1 && cc >= 4);
}
__host__ __device__ __forceinline__ constexpr int vg_slot(int jq) {
  int cc = jq >> 2, q = jq & 3;
  return (q == 0) ? cc : 16 + (cc - 4);
}
__host__ __device__ __forceinline__ constexpr bool is_lds_q(int jq) {
  int cc = jq >> 2, q = jq & 3;
  return (q == 3) || (q == 2 && cc >= 13);
}
__host__ __device__ __forceinline__ constexpr int lds_slot(int jq) {
  int cc = jq >> 2, q = jq & 3;
  return (q == 3) ? cc : 16 + (cc - 13);
}
__host__ __device__ __forceinline__ constexpr int str_slot(int jq) {
  int cc = jq >> 2, q = jq & 3;
  return (q == 1) ? cc : 4 + cc;           // q1 cc0..3 -> 0..3; q2 cc0..12 -> 4..16
}

__device__ __forceinline__ float fdot2(unsigned int a, unsigned int b, float c) {
  return __builtin_amdgcn_fdot2(__builtin_bit_cast(half2v, a),
                                __builtin_bit_cast(half2v, b), c, false);
}

__device__ __forceinline__ unsigned int pack_h2(float a, float b) {
  unsigned short ua = __half_as_ushort(__float2half(a));
  unsigned short ub = __half_as_ushort(__float2half(b));
  return (unsigned int)ua | ((unsigned int)ub << 16);
}

__device__ __forceinline__ float sigmoid_f(float x) {
  return __fdividef(1.0f, 1.0f + __expf(-x));
}
__device__ __forceinline__ float tanh_f(float x) {
  float ax = fminf(fabsf(x) * 2.0f, 40.0f);
  float e = __expf(ax);
  float r = __fdividef(e - 1.0f, e + 1.0f);
  return copysignf(r, x);
}

// ---------------- K0: weight packing / permutation ----------------
__global__ __launch_bounds__(256) void k0_pack(
    const float* __restrict__ wih, const float* __restrict__ whh,
    const float* __restrict__ bih, const float* __restrict__ bhh,
    const float* __restrict__ wfc,
    float* __restrict__ wpih, float* __restrict__ biasp,
    unsigned int* __restrict__ wreg_ws, unsigned int* __restrict__ wlds_ws,
    unsigned int* __restrict__ wstr_ws, unsigned int* __restrict__ wfcp) {
  int idx = blockIdx.x * 256 + threadIdx.x;
  if (idx < 61440) {                       // Wp_ih[k][r'] = W_ih[orig(r')][k]
    int k = idx / 1024, rp = idx % 1024;
    int orig = (rp & 3) * 256 + (rp >> 2);
    wpih[idx] = wih[orig * IN_ + k];
  } else if (idx < 62464) {                // bias_p[r'] = b_ih[orig]+b_hh[orig]
    int rp = idx - 61440;
    int orig = (rp & 3) * 256 + (rp >> 2);
    biasp[rp] = bih[orig] + bhh[orig];
  } else if (idx < 193536) {               // W_hh -> f16 pairs, k2 layout
    int i2 = idx - 62464;                  // 0..131071
    int l = i2 >> 8;                       // k2 thread 0..511
    int i = i2 & 255;                      // dword within thread
    int jq = i >> 2, p = i & 3;
    int cc = jq >> 2, q = jq & 3;
    int u = l >> 1, hf = l & 1;
    int P = hf * 64 + cc * 4 + p;          // k-pair index: covers k=2P,2P+1
    int row = q * 256 + u;                 // original gate row
    unsigned int pk = pack_h2(whh[row * 256 + 2 * P], whh[row * 256 + 2 * P + 1]);
    if (is_vgpr_q(jq))     wreg_ws[(vg_slot(jq) * 512 + l) * 4 + p] = pk;
    else if (is_lds_q(jq)) wlds_ws[(lds_slot(jq) * 512 + l) * 4 + p] = pk;
    else                   wstr_ws[(str_slot(jq) * 512 + l) * 4 + p] = pk;
  } else if (idx < 244992) {               // W_fc -> f16 pairs
    int i3 = idx - 193536;
    int o = i3 >> 7, P = i3 & 127;
    wfcp[o * 128 + P] = pack_h2(wfc[o * 256 + 2 * P], wfc[o * 256 + 2 * P + 1]);
  }
}

// ---------------- K1: xg = x @ W_ih^T + b_ih + b_hh (permuted cols) ---------
template <bool F32>
__global__ __launch_bounds__(256, 2) void k1_xgemm(
    const float* __restrict__ x, const float* __restrict__ wpih,
    const float* __restrict__ biasp, void* __restrict__ xg_v) {
  __shared__ float xt[IN_ * 64];           // xt[k][bt]
  const int l = threadIdx.x, blk = blockIdx.x;
  for (int i = l; i < IN_ * 64; i += 256) {
    int k = i >> 6, bt = i & 63;
    xt[i] = x[(size_t)(blk * 64 + bt) * IN_ + k];
  }
  __syncthreads();
  float4 bias4 = *(const float4*)&biasp[4 * l];
  float* xg_f = (float*)xg_v;
  unsigned int* xg_h = (unsigned int*)xg_v;
  for (int half = 0; half < 2; ++half) {   // 2 chunks of 32 bt-rows
    float4 a[32];
#pragma unroll
    for (int j = 0; j < 32; ++j) a[j] = bias4;
    for (int k = 0; k < IN_; ++k) {
      float4 w4 = *(const float4*)&wpih[k * G4_ + 4 * l];
#pragma unroll
      for (int j4 = 0; j4 < 8; ++j4) {
        float4 xv = *(const float4*)&xt[k * 64 + half * 32 + j4 * 4];
        float xs[4] = {xv.x, xv.y, xv.z, xv.w};
#pragma unroll
        for (int jj = 0; jj < 4; ++jj) {
          float xc = xs[jj];
          float4& A = a[j4 * 4 + jj];
          A.x = fmaf(w4.x, xc, A.x); A.y = fmaf(w4.y, xc, A.y);
          A.z = fmaf(w4.z, xc, A.z); A.w = fmaf(w4.w, xc, A.w);
        }
      }
    }
#pragma unroll
    for (int j = 0; j < 32; ++j) {
      size_t bt = (size_t)blk * 64 + half * 32 + j;
      if constexpr (F32) {
        *(float4*)&xg_f[bt * G4_ + 4 * l] = a[j];
      } else {
        uint2 pk;
        pk.x = pack_h2(a[j].x, a[j].y);
        pk.y = pack_h2(a[j].z, a[j].w);
        *(uint2*)&xg_h[bt * (G4_ / 2) + 2 * l] = pk;
      }
    }
  }
}

// ---------------- K2: sequential LSTM, 1 block per batch row ----------------
// 512 threads = 8 waves = 2 waves/SIMD (256 unified regs/thread budget).
// Thread l = (u=l>>1, hf=l&1): all 4 gates of unit u over 128 k values.
// Weights three-tier: 112 dwords plain-VGPR resident (112 + ~124 arch working
// fits the 256 budget -> no spill, no remat, free reads), 76 dwords LDS,
// 68 dwords streamed from L2 per step (139 KB/block/step). Tiers interleaved
// per chunk so VALU/LDS/L2 pipes overlap.
template <bool F32>
__global__ __launch_bounds__(512, 2) void k2_lstm(
    const void* __restrict__ xg_v, const uint4* __restrict__ wreg_ws,
    const uint4* __restrict__ wlds_ws, const uint4* __restrict__ wstr_ws,
    unsigned short* __restrict__ hs) {
  __shared__ uint4 wlds[NLDSQ * 512];                   // 155648 B
  __shared__ unsigned int hq4[2][2][68];                // padded h dbuf, 1088 B
  const int l = threadIdx.x;
  const int b = blockIdx.x;
  const int hf = l & 1;
  for (int i = l; i < NLDSQ * 512; i += 512) wlds[i] = wlds_ws[i];
  if (l < 64)        hq4[0][0][l] = 0u;                 // h(0) = 0
  else if (l < 128)  hq4[0][1][l - 64] = 0u;

  uint4 wr[NREGQ];                                      // 112 resident dwords
#pragma unroll
  for (int j = 0; j < NREGQ; ++j) {
    wr[j] = wreg_ws[j * 512 + l];
    asm("" : "+v"(wr[j].x));                            // opaque -> no remat
    asm("" : "+v"(wr[j].y));
    asm("" : "+v"(wr[j].z));
    asm("" : "+v"(wr[j].w));
  }

  const unsigned int* xgu = (const unsigned int*)xg_v;  // f16: dword bt*512+l
  const float2* xgf2 = (const float2*)xg_v;             // f32: float2 bt*512+l
  float2 xf2; unsigned int xh;
  if constexpr (F32) xf2 = xgf2[(size_t)b * T_ * 512 + l];
  else               xh  = xgu[(size_t)b * T_ * 512 + l];
  float c = 0.0f;
  __syncthreads();
  for (int t = 0; t < T_; ++t) {
    float lo, hi;
    if constexpr (F32) { lo = xf2.x; hi = xf2.y; }
    else {
      half2v p = __builtin_bit_cast(half2v, xh);
      lo = (float)p[0]; hi = (float)p[1];
    }
    // hf=0 lane seeds gates i,f; hf=1 lane seeds gates g,o
    float a0 = hf ? 0.0f : lo, a1 = hf ? 0.0f : hi;
    float a2 = hf ? lo : 0.0f, a3 = hf ? hi : 0.0f;
    int tn = (t < T_ - 1) ? (t + 1) : t;                // prefetch next xg
    if constexpr (F32) xf2 = xgf2[(size_t)(b * T_ + tn) * 512 + l];
    else               xh  = xgu[(size_t)(b * T_ + tn) * 512 + l];

    const uint4* hB = (const uint4*)hq4[t & 1][hf];     // 16 quads of h-half
#pragma unroll
    for (int cc = 0; cc < 16; ++cc) {
      uint4 hq = hB[cc];
#pragma unroll
      for (int q = 0; q < 4; ++q) {
        const int jq = cc * 4 + q;
        uint4 w;
        if (is_vgpr_q(jq))     w = wr[vg_slot(jq)];
        else if (is_lds_q(jq)) w = wlds[lds_slot(jq) * 512 + l];
        else                   w = wstr_ws[str_slot(jq) * 512 + l];
        float& aq = (q == 0) ? a0 : (q == 1) ? a1 : (q == 2) ? a2 : a3;
        aq = fdot2(w.x, hq.x, aq); aq = fdot2(w.y, hq.y, aq);
        aq = fdot2(w.z, hq.z, aq); aq = fdot2(w.w, hq.w, aq);
      }
    }
    // combine the two k-halves (partner lane adjacent in same wave)
    a0 += __shfl_xor(a0, 1); a1 += __shfl_xor(a1, 1);
    a2 += __shfl_xor(a2, 1); a3 += __shfl_xor(a3, 1);
    // gating (redundant on both lanes of the pair)
    float ig = sigmoid_f(a0), fg = sigmoid_f(a1);
    float gg = tanh_f(a2),    og = sigmoid_f(a3);
    c = fg * c + ig * gg;
    float h = og * tanh_f(c);
    unsigned int hbits = (unsigned int)__half_as_ushort(__float2half(h));
    unsigned int hnext = (unsigned int)__shfl_xor((int)hbits, 2); // unit u+1
    if ((l & 3) == 0) {                                 // one dword per 2 units
      unsigned int pk = hbits | (hnext << 16);
      int d = l >> 2;                                   // dword 0..127
      hq4[(t & 1) ^ 1][d >> 6][d & 63] = pk;
      ((unsigned int*)hs)[(size_t)(b * T_ + t) * 128 + d] = pk;
    }
    __syncthreads();                                    // h(t) visible to all
  }
}

// ---------------- K3: out = hs @ W_fc^T + b_fc ----------------
__global__ __launch_bounds__(256, 2) void k3_out(
    const unsigned short* __restrict__ hs, const unsigned int* __restrict__ wfcp,
    const float* __restrict__ bfc, float* __restrict__ out) {
  __shared__ unsigned int ht[64 * 128];            // 64 bt-rows of h (f16 pairs)
  const int l = threadIdx.x, blk = blockIdx.x;
  const unsigned int* hsrc = (const unsigned int*)hs + (size_t)blk * 64 * 128;
  for (int i = l; i < 64 * 128; i += 256) ht[i] = hsrc[i];
  __syncthreads();
  const int c1 = l;
  const int c2 = 256 + l;
  const bool has2 = (c2 < O_);
  const int c2r = has2 ? c2 : 0;
  float b1 = bfc[c1], b2 = bfc[c2r];
  for (int btc = 0; btc < 4; ++btc) {
    float a1[16], a2[16];
#pragma unroll
    for (int j = 0; j < 16; ++j) { a1[j] = b1; a2[j] = b2; }
    for (int Pc = 0; Pc < 8; ++Pc) {
      uint4 wq1[4], wq2[4];
#pragma unroll
      for (int p4 = 0; p4 < 4; ++p4) {
        wq1[p4] = *(const uint4*)&wfcp[c1 * 128 + Pc * 16 + 4 * p4];
        wq2[p4] = *(const uint4*)&wfcp[c2r * 128 + Pc * 16 + 4 * p4];
      }
#pragma unroll
      for (int j = 0; j < 16; ++j) {
        const unsigned int* hr = &ht[(btc * 16 + j) * 128 + Pc * 16];
#pragma unroll
        for (int p4 = 0; p4 < 4; ++p4) {
          uint4 hv = *(const uint4*)&hr[4 * p4];
          a1[j] = fdot2(wq1[p4].x, hv.x, a1[j]);
          a1[j] = fdot2(wq1[p4].y, hv.y, a1[j]);
          a1[j] = fdot2(wq1[p4].z, hv.z, a1[j]);
          a1[j] = fdot2(wq1[p4].w, hv.w, a1[j]);
          a2[j] = fdot2(wq2[p4].x, hv.x, a2[j]);
          a2[j] = fdot2(wq2[p4].y, hv.y, a2[j]);
          a2[j] = fdot2(wq2[p4].z, hv.z, a2[j]);
          a2[j] = fdot2(wq2[p4].w, hv.w, a2[j]);
        }
      }
    }
#pragma unroll
    for (int j = 0; j < 16; ++j) {
      size_t bt = (size_t)blk * 64 + btc * 16 + j;
      out[bt * O_ + c1] = a1[j];
      if (has2) out[bt * O_ + c2] = a2[j];
    }
  }
}

// ---------------- host ----------------
extern "C" void kernel_launch(void* const* d_in, const int* in_sizes, int n_in,
                              void* d_out, int out_size, void* d_ws, size_t ws_size,
                              hipStream_t stream) {
  const float* x   = (const float*)d_in[0];
  const float* wih = (const float*)d_in[1];
  const float* whh = (const float*)d_in[2];
  const float* bih = (const float*)d_in[3];
  const float* bhh = (const float*)d_in[4];
  const float* wfc = (const float*)d_in[5];
  const float* bfc = (const float*)d_in[6];
  float* out = (float*)d_out;
  char* ws = (char*)d_ws;

  const size_t HS_BYTES = (size_t)B_ * T_ * H_ * 2;
  const size_t XG_F32   = (size_t)B_ * T_ * G4_ * 4;
  const size_t WREG_B   = (size_t)NREGQ * 512 * 16;  // 229376
  const size_t WLDS_B   = (size_t)NLDSQ * 512 * 16;  // 155648
  const size_t WSTR_B   = (size_t)NSTRQ * 512 * 16;  // 139264
  const size_t WPIH_B   = (size_t)IN_ * G4_ * 4;
  const size_t BIAS_B   = (size_t)G4_ * 4;
  const size_t WFCP_B   = (size_t)O_ * 128 * 4;
  const size_t TAIL = HS_BYTES + WREG_B + WLDS_B + WSTR_B + WPIH_B + BIAS_B + WFCP_B;

  bool f32xg = (ws_size >= XG_F32 + TAIL);
  size_t xg_bytes = f32xg ? XG_F32 : ((size_t)B_ * T_ * G4_ * 2);

  char* xg    = ws;
  char* hsb   = ws + xg_bytes;
  char* wregp = hsb + HS_BYTES;
  char* wldsp = wregp + WREG_B;
  char* wstrp = wldsp + WLDS_B;
  char* wpihp = wstrp + WSTR_B;
  char* biasp = wpihp + WPIH_B;
  char* wfcpp = biasp + BIAS_B;

  hipLaunchKernelGGL(k0_pack, dim3(957), dim3(256), 0, stream,
                     wih, whh, bih, bhh, wfc,
                     (float*)wpihp, (float*)biasp,
                     (unsigned int*)wregp, (unsigned int*)wldsp,
                     (unsigned int*)wstrp, (unsigned int*)wfcpp);
  if (f32xg) {
    hipLaunchKernelGGL((k1_xgemm<true>), dim3(512), dim3(256), 0, stream,
                       x, (const float*)wpihp, (const float*)biasp, (void*)xg);
    hipLaunchKernelGGL((k2_lstm<true>), dim3(64), dim3(512), 0, stream,
                       (const void*)xg, (const uint4*)wregp, (const uint4*)wldsp,
                       (const uint4*)wstrp, (unsigned short*)hsb);
  } else {
    hipLaunchKernelGGL((k1_xgemm<false>), dim3(512), dim3(256), 0, stream,
                       x, (const float*)wpihp, (const float*)biasp, (void*)xg);
    hipLaunchKernelGGL((k2_lstm<false>), dim3(64), dim3(512), 0, stream,
                       (const void*)xg, (const uint4*)wregp, (const uint4*)wldsp,
                       (const uint4*)wstrp, (unsigned short*)hsb);
  }
  hipLaunchKernelGGL(k3_out, dim3(512), dim3(256), 0, stream,
                     (const unsigned short*)hsb, (const unsigned int*)wfcpp,
                     bfc, out);
}

// Round 9
// 963.493 us; speedup vs baseline: 1.5302x; 1.0003x over previous
//
#include <hip/hip_runtime.h>
#include <hip/hip_fp16.h>

typedef _Float16 half2v __attribute__((ext_vector_type(2)));

#define B_ 64
#define T_ 512
#define H_ 256
#define G4_ 1024
#define IN_ 60
#define O_ 402

#define NREGQ 28   // weight quads per thread in plain VGPRs (112 dwords)
#define NLDSQ 19   // weight quads per thread in LDS (155648 B)
#define NSTRQ 17   // weight quads per thread streamed from L2 each step

// Quad routing: quad jq = cc*4+q (cc = k-chunk 0..15, q = gate 0..3).
//  VGPR:   q==0 (all cc)        + q==1 (cc>=4)   -> 28 quads
//  LDS:    q==3 (all cc)        + q==2 (cc>=13)  -> 19 quads
//  STREAM: q==1 (cc<4)          + q==2 (cc<13)   -> 17 quads
// Interleaved across chunks so VGPR/LDS/L2 pipes overlap every chunk.
__host__ __device__ __forceinline__ constexpr bool is_vgpr_q(int jq) {
  int cc = jq >> 2, q = jq & 3;
  return (q == 0) || (q == 1 && cc >= 4);
}
__host__ __device__ __forceinline__ constexpr int vg_slot(int jq) {
  int cc = jq >> 2, q = jq & 3;
  return (q == 0) ? cc : 16 + (cc - 4);
}
__host__ __device__ __forceinline__ constexpr bool is_lds_q(int jq) {
  int cc = jq >> 2, q = jq & 3;
  return (q == 3) || (q == 2 && cc >= 13);
}
__host__ __device__ __forceinline__ constexpr int lds_slot(int jq) {
  int cc = jq >> 2, q = jq & 3;
  return (q == 3) ? cc : 16 + (cc - 13);
}
__host__ __device__ __forceinline__ constexpr int str_slot(int jq) {
  int cc = jq >> 2, q = jq & 3;
  return (q == 1) ? cc : 4 + cc;           // q1 cc0..3 -> 0..3; q2 cc0..12 -> 4..16
}

__device__ __forceinline__ float fdot2(unsigned int a, unsigned int b, float c) {
  return __builtin_amdgcn_fdot2(__builtin_bit_cast(half2v, a),
                                __builtin_bit_cast(half2v, b), c, false);
}

__device__ __forceinline__ unsigned int pack_h2(float a, float b) {
  unsigned short ua = __half_as_ushort(__float2half(a));
  unsigned short ub = __half_as_ushort(__float2half(b));
  return (unsigned int)ua | ((unsigned int)ub << 16);
}

__device__ __forceinline__ float sigmoid_f(float x) {
  return __fdividef(1.0f, 1.0f + __expf(-x));
}
__device__ __forceinline__ float tanh_f(float x) {
  float ax = fminf(fabsf(x) * 2.0f, 40.0f);
  float e = __expf(ax);
  float r = __fdividef(e - 1.0f, e + 1.0f);
  return copysignf(r, x);
}

// ---------------- K0: weight packing / permutation ----------------
__global__ __launch_bounds__(256) void k0_pack(
    const float* __restrict__ wih, const float* __restrict__ whh,
    const float* __restrict__ bih, const float* __restrict__ bhh,
    const float* __restrict__ wfc,
    float* __restrict__ wpih, float* __restrict__ biasp,
    unsigned int* __restrict__ wreg_ws, unsigned int* __restrict__ wlds_ws,
    unsigned int* __restrict__ wstr_ws, unsigned int* __restrict__ wfcp) {
  int idx = blockIdx.x * 256 + threadIdx.x;
  if (idx < 61440) {                       // Wp_ih[k][r'] = W_ih[orig(r')][k]
    int k = idx / 1024, rp = idx % 1024;
    int orig = (rp & 3) * 256 + (rp >> 2);
    wpih[idx] = wih[orig * IN_ + k];
  } else if (idx < 62464) {                // bias_p[r'] = b_ih[orig]+b_hh[orig]
    int rp = idx - 61440;
    int orig = (rp & 3) * 256 + (rp >> 2);
    biasp[rp] = bih[orig] + bhh[orig];
  } else if (idx < 193536) {               // W_hh -> f16 pairs, k2 layout
    int i2 = idx - 62464;                  // 0..131071
    int l = i2 >> 8;                       // k2 thread 0..511
    int i = i2 & 255;                      // dword within thread
    int jq = i >> 2, p = i & 3;
    int cc = jq >> 2, q = jq & 3;
    int u = l >> 1, hf = l & 1;
    int P = hf * 64 + cc * 4 + p;          // k-pair index: covers k=2P,2P+1
    int row = q * 256 + u;                 // original gate row
    unsigned int pk = pack_h2(whh[row * 256 + 2 * P], whh[row * 256 + 2 * P + 1]);
    if (is_vgpr_q(jq))     wreg_ws[(vg_slot(jq) * 512 + l) * 4 + p] = pk;
    else if (is_lds_q(jq)) wlds_ws[(lds_slot(jq) * 512 + l) * 4 + p] = pk;
    else                   wstr_ws[(str_slot(jq) * 512 + l) * 4 + p] = pk;
  } else if (idx < 244992) {               // W_fc -> f16 pairs
    int i3 = idx - 193536;
    int o = i3 >> 7, P = i3 & 127;
    wfcp[o * 128 + P] = pack_h2(wfc[o * 256 + 2 * P], wfc[o * 256 + 2 * P + 1]);
  }
}

// ---------------- K1: xg = x @ W_ih^T + b_ih + b_hh (permuted cols) ---------
template <bool F32>
__global__ __launch_bounds__(256, 2) void k1_xgemm(
    const float* __restrict__ x, const float* __restrict__ wpih,
    const float* __restrict__ biasp, void* __restrict__ xg_v) {
  __shared__ float xt[IN_ * 64];           // xt[k][bt]
  const int l = threadIdx.x, blk = blockIdx.x;
  for (int i = l; i < IN_ * 64; i += 256) {
    int k = i >> 6, bt = i & 63;
    xt[i] = x[(size_t)(blk * 64 + bt) * IN_ + k];
  }
  __syncthreads();
  float4 bias4 = *(const float4*)&biasp[4 * l];
  float* xg_f = (float*)xg_v;
  unsigned int* xg_h = (unsigned int*)xg_v;
  for (int half = 0; half < 2; ++half) {   // 2 chunks of 32 bt-rows
    float4 a[32];
#pragma unroll
    for (int j = 0; j < 32; ++j) a[j] = bias4;
    for (int k = 0; k < IN_; ++k) {
      float4 w4 = *(const float4*)&wpih[k * G4_ + 4 * l];
#pragma unroll
      for (int j4 = 0; j4 < 8; ++j4) {
        float4 xv = *(const float4*)&xt[k * 64 + half * 32 + j4 * 4];
        float xs[4] = {xv.x, xv.y, xv.z, xv.w};
#pragma unroll
        for (int jj = 0; jj < 4; ++jj) {
          float xc = xs[jj];
          float4& A = a[j4 * 4 + jj];
          A.x = fmaf(w4.x, xc, A.x); A.y = fmaf(w4.y, xc, A.y);
          A.z = fmaf(w4.z, xc, A.z); A.w = fmaf(w4.w, xc, A.w);
        }
      }
    }
#pragma unroll
    for (int j = 0; j < 32; ++j) {
      size_t bt = (size_t)blk * 64 + half * 32 + j;
      if constexpr (F32) {
        *(float4*)&xg_f[bt * G4_ + 4 * l] = a[j];
      } else {
        uint2 pk;
        pk.x = pack_h2(a[j].x, a[j].y);
        pk.y = pack_h2(a[j].z, a[j].w);
        *(uint2*)&xg_h[bt * (G4_ / 2) + 2 * l] = pk;
      }
    }
  }
}

// ---------------- K2: sequential LSTM, 1 block per batch row ----------------
// 512 threads = 8 waves = 2 waves/SIMD. amdgpu_waves_per_eu(2,2) pins the
// allocator to EXACTLY 2 waves/EU (256-reg budget): without it LLVM targets
// the 4-wave tier (128 regs) and spills the weight array to scratch -- the
// r4/r6/r7/r8 failure mode (VGPR_Count 116-124, just under 128).
// Thread l = (u=l>>1, hf=l&1): all 4 gates of unit u over 128 k values.
// Weights three-tier: 112 dwords plain-VGPR resident, 76 dwords LDS,
// 68 dwords streamed from L2 per step. Tiers interleaved per chunk.
template <bool F32>
__global__ __attribute__((amdgpu_waves_per_eu(2, 2))) __launch_bounds__(512)
void k2_lstm(
    const void* __restrict__ xg_v, const uint4* __restrict__ wreg_ws,
    const uint4* __restrict__ wlds_ws, const uint4* __restrict__ wstr_ws,
    unsigned short* __restrict__ hs) {
  __shared__ uint4 wlds[NLDSQ * 512];                   // 155648 B
  __shared__ unsigned int hq4[2][2][68];                // padded h dbuf, 1088 B
  const int l = threadIdx.x;
  const int b = blockIdx.x;
  const int hf = l & 1;
  for (int i = l; i < NLDSQ * 512; i += 512) wlds[i] = wlds_ws[i];
  if (l < 64)        hq4[0][0][l] = 0u;                 // h(0) = 0
  else if (l < 128)  hq4[0][1][l - 64] = 0u;

  uint4 wr[NREGQ];                                      // 112 resident dwords
#pragma unroll
  for (int j = 0; j < NREGQ; ++j) {
    wr[j] = wreg_ws[j * 512 + l];
    asm("" : "+v"(wr[j].x));                            // opaque -> no remat
    asm("" : "+v"(wr[j].y));
    asm("" : "+v"(wr[j].z));
    asm("" : "+v"(wr[j].w));
  }

  const unsigned int* xgu = (const unsigned int*)xg_v;  // f16: dword bt*512+l
  const float2* xgf2 = (const float2*)xg_v;             // f32: float2 bt*512+l
  float2 xf2; unsigned int xh;
  if constexpr (F32) xf2 = xgf2[(size_t)b * T_ * 512 + l];
  else               xh  = xgu[(size_t)b * T_ * 512 + l];
  float c = 0.0f;
  __syncthreads();
  for (int t = 0; t < T_; ++t) {
    float lo, hi;
    if constexpr (F32) { lo = xf2.x; hi = xf2.y; }
    else {
      half2v p = __builtin_bit_cast(half2v, xh);
      lo = (float)p[0]; hi = (float)p[1];
    }
    // hf=0 lane seeds gates i,f; hf=1 lane seeds gates g,o
    float a0 = hf ? 0.0f : lo, a1 = hf ? 0.0f : hi;
    float a2 = hf ? lo : 0.0f, a3 = hf ? hi : 0.0f;
    int tn = (t < T_ - 1) ? (t + 1) : t;                // prefetch next xg
    if constexpr (F32) xf2 = xgf2[(size_t)(b * T_ + tn) * 512 + l];
    else               xh  = xgu[(size_t)(b * T_ + tn) * 512 + l];

    const uint4* hB = (const uint4*)hq4[t & 1][hf];     // 16 quads of h-half
#pragma unroll
    for (int cc = 0; cc < 16; ++cc) {
      uint4 hq = hB[cc];
#pragma unroll
      for (int q = 0; q < 4; ++q) {
        const int jq = cc * 4 + q;
        uint4 w;
        if (is_vgpr_q(jq))     w = wr[vg_slot(jq)];
        else if (is_lds_q(jq)) w = wlds[lds_slot(jq) * 512 + l];
        else                   w = wstr_ws[str_slot(jq) * 512 + l];
        float& aq = (q == 0) ? a0 : (q == 1) ? a1 : (q == 2) ? a2 : a3;
        aq = fdot2(w.x, hq.x, aq); aq = fdot2(w.y, hq.y, aq);
        aq = fdot2(w.z, hq.z, aq); aq = fdot2(w.w, hq.w, aq);
      }
    }
    // combine the two k-halves (partner lane adjacent in same wave)
    a0 += __shfl_xor(a0, 1); a1 += __shfl_xor(a1, 1);
    a2 += __shfl_xor(a2, 1); a3 += __shfl_xor(a3, 1);
    // gating (redundant on both lanes of the pair)
    float ig = sigmoid_f(a0), fg = sigmoid_f(a1);
    float gg = tanh_f(a2),    og = sigmoid_f(a3);
    c = fg * c + ig * gg;
    float h = og * tanh_f(c);
    unsigned int hbits = (unsigned int)__half_as_ushort(__float2half(h));
    unsigned int hnext = (unsigned int)__shfl_xor((int)hbits, 2); // unit u+1
    if ((l & 3) == 0) {                                 // one dword per 2 units
      unsigned int pk = hbits | (hnext << 16);
      int d = l >> 2;                                   // dword 0..127
      hq4[(t & 1) ^ 1][d >> 6][d & 63] = pk;
      ((unsigned int*)hs)[(size_t)(b * T_ + t) * 128 + d] = pk;
    }
    __syncthreads();                                    // h(t) visible to all
  }
}

// ---------------- K3: out = hs @ W_fc^T + b_fc ----------------
__global__ __launch_bounds__(256, 2) void k3_out(
    const unsigned short* __restrict__ hs, const unsigned int* __restrict__ wfcp,
    const float* __restrict__ bfc, float* __restrict__ out) {
  __shared__ unsigned int ht[64 * 128];            // 64 bt-rows of h (f16 pairs)
  const int l = threadIdx.x, blk = blockIdx.x;
  const unsigned int* hsrc = (const unsigned int*)hs + (size_t)blk * 64 * 128;
  for (int i = l; i < 64 * 128; i += 256) ht[i] = hsrc[i];
  __syncthreads();
  const int c1 = l;
  const int c2 = 256 + l;
  const bool has2 = (c2 < O_);
  const int c2r = has2 ? c2 : 0;
  float b1 = bfc[c1], b2 = bfc[c2r];
  for (int btc = 0; btc < 4; ++btc) {
    float a1[16], a2[16];
#pragma unroll
    for (int j = 0; j < 16; ++j) { a1[j] = b1; a2[j] = b2; }
    for (int Pc = 0; Pc < 8; ++Pc) {
      uint4 wq1[4], wq2[4];
#pragma unroll
      for (int p4 = 0; p4 < 4; ++p4) {
        wq1[p4] = *(const uint4*)&wfcp[c1 * 128 + Pc * 16 + 4 * p4];
        wq2[p4] = *(const uint4*)&wfcp[c2r * 128 + Pc * 16 + 4 * p4];
      }
#pragma unroll
      for (int j = 0; j < 16; ++j) {
        const unsigned int* hr = &ht[(btc * 16 + j) * 128 + Pc * 16];
#pragma unroll
        for (int p4 = 0; p4 < 4; ++p4) {
          uint4 hv = *(const uint4*)&hr[4 * p4];
          a1[j] = fdot2(wq1[p4].x, hv.x, a1[j]);
          a1[j] = fdot2(wq1[p4].y, hv.y, a1[j]);
          a1[j] = fdot2(wq1[p4].z, hv.z, a1[j]);
          a1[j] = fdot2(wq1[p4].w, hv.w, a1[j]);
          a2[j] = fdot2(wq2[p4].x, hv.x, a2[j]);
          a2[j] = fdot2(wq2[p4].y, hv.y, a2[j]);
          a2[j] = fdot2(wq2[p4].z, hv.z, a2[j]);
          a2[j] = fdot2(wq2[p4].w, hv.w, a2[j]);
        }
      }
    }
#pragma unroll
    for (int j = 0; j < 16; ++j) {
      size_t bt = (size_t)blk * 64 + btc * 16 + j;
      out[bt * O_ + c1] = a1[j];
      if (has2) out[bt * O_ + c2] = a2[j];
    }
  }
}

// ---------------- host ----------------
extern "C" void kernel_launch(void* const* d_in, const int* in_sizes, int n_in,
                              void* d_out, int out_size, void* d_ws, size_t ws_size,
                              hipStream_t stream) {
  const float* x   = (const float*)d_in[0];
  const float* wih = (const float*)d_in[1];
  const float* whh = (const float*)d_in[2];
  const float* bih = (const float*)d_in[3];
  const float* bhh = (const float*)d_in[4];
  const float* wfc = (const float*)d_in[5];
  const float* bfc = (const float*)d_in[6];
  float* out = (float*)d_out;
  char* ws = (char*)d_ws;

  const size_t HS_BYTES = (size_t)B_ * T_ * H_ * 2;
  const size_t XG_F32   = (size_t)B_ * T_ * G4_ * 4;
  const size_t WREG_B   = (size_t)NREGQ * 512 * 16;  // 229376
  const size_t WLDS_B   = (size_t)NLDSQ * 512 * 16;  // 155648
  const size_t WSTR_B   = (size_t)NSTRQ * 512 * 16;  // 139264
  const size_t WPIH_B   = (size_t)IN_ * G4_ * 4;
  const size_t BIAS_B   = (size_t)G4_ * 4;
  const size_t WFCP_B   = (size_t)O_ * 128 * 4;
  const size_t TAIL = HS_BYTES + WREG_B + WLDS_B + WSTR_B + WPIH_B + BIAS_B + WFCP_B;

  bool f32xg = (ws_size >= XG_F32 + TAIL);
  size_t xg_bytes = f32xg ? XG_F32 : ((size_t)B_ * T_ * G4_ * 2);

  char* xg    = ws;
  char* hsb   = ws + xg_bytes;
  char* wregp = hsb + HS_BYTES;
  char* wldsp = wregp + WREG_B;
  char* wstrp = wldsp + WLDS_B;
  char* wpihp = wstrp + WSTR_B;
  char* biasp = wpihp + WPIH_B;
  char* wfcpp = biasp + BIAS_B;

  hipLaunchKernelGGL(k0_pack, dim3(957), dim3(256), 0, stream,
                     wih, whh, bih, bhh, wfc,
                     (float*)wpihp, (float*)biasp,
                     (unsigned int*)wregp, (unsigned int*)wldsp,
                     (unsigned int*)wstrp, (unsigned int*)wfcpp);
  if (f32xg) {
    hipLaunchKernelGGL((k1_xgemm<true>), dim3(512), dim3(256), 0, stream,
                       x, (const float*)wpihp, (const float*)biasp, (void*)xg);
    hipLaunchKernelGGL((k2_lstm<true>), dim3(64), dim3(512), 0, stream,
                       (const void*)xg, (const uint4*)wregp, (const uint4*)wldsp,
                       (const uint4*)wstrp, (unsigned short*)hsb);
  } else {
    hipLaunchKernelGGL((k1_xgemm<false>), dim3(512), dim3(256), 0, stream,
                       x, (const float*)wpihp, (const float*)biasp, (void*)xg);
    hipLaunchKernelGGL((k2_lstm<false>), dim3(64), dim3(512), 0, stream,
                       (const void*)xg, (const uint4*)wregp, (const uint4*)wldsp,
                       (const uint4*)wstrp, (unsigned short*)hsb);
  }
  hipLaunchKernelGGL(k3_out, dim3(512), dim3(256), 0, stream,
                     (const unsigned short*)hsb, (const unsigned int*)wfcpp,
                     bfc, out);
}